// Round 10
// baseline (230.103 us; speedup 1.0000x reference)
//
#include <hip/hip_runtime.h>
#include <hip/hip_bf16.h>
#include <math.h>

typedef unsigned short ushort_t;
typedef __attribute__((ext_vector_type(8))) short bf16x8;
typedef __attribute__((ext_vector_type(4))) float f32x4;
typedef __attribute__((ext_vector_type(2))) float f32x2;

constexpr int BATCH   = 4;
constexpr int D_MODEL = 256;
constexpr int LEN_IN  = 5440;
constexpr int LEN_Q   = 5440;
constexpr int M_TOT   = BATCH * LEN_Q;   // 21760

#define ASG __attribute__((address_space(1)))
#define ASL __attribute__((address_space(3)))

__device__ __forceinline__ void gld16(const void* g, void* l) {
    __builtin_amdgcn_global_load_lds((ASG const void*)g, (ASL void*)l, 16, 0, 0);
}

__device__ __forceinline__ ushort_t bfbits(float x) {
    __hip_bfloat16 h = __float2bfloat16(x);
    ushort_t u; __builtin_memcpy(&u, &h, 2); return u;
}
__device__ __forceinline__ unsigned pk2(float a, float b) {
    return (unsigned)bfbits(a) | ((unsigned)bfbits(b) << 16);
}

// ======================= weight prep (tiny) =======================
__global__ __launch_bounds__(256) void pack_weights(
    const float* __restrict__ Wv, const float* __restrict__ Wout,
    const float* __restrict__ Wo, const float* __restrict__ Wa,
    const float* __restrict__ b_off, const float* __restrict__ b_attn,
    ushort_t* __restrict__ wvT, ushort_t* __restrict__ woutT,
    ushort_t* __restrict__ woaT, float* __restrict__ bias_oa)
{
    const int blk = blockIdx.x, t = threadIdx.x;
    if (blk < 64) {
        const float* src = (blk < 32) ? Wv : Wout;
        ushort_t*    dst = (blk < 32) ? wvT : woutT;
        const int k0 = (blk & 31) * 8;
        float f[8];
#pragma unroll
        for (int i = 0; i < 8; i++) f[i] = src[(k0 + i) * 256 + t];
        *(uint4*)(dst + t * 256 + k0) =
            make_uint4(pk2(f[0], f[1]), pk2(f[2], f[3]),
                       pk2(f[4], f[5]), pk2(f[6], f[7]));
    } else if (blk < 96) {
        const int k0 = (blk - 64) * 8;
#pragma unroll
        for (int rep = 0; rep < 2; rep++) {
            const int j = (rep == 0) ? t : 256 + t;
            if (rep == 1 && t >= 128) break;
            float f[8];
#pragma unroll
            for (int i = 0; i < 8; i++)
                f[i] = (j < 256) ? Wo[(k0 + i) * 256 + j]
                                 : Wa[(k0 + i) * 128 + (j - 256)];
            *(uint4*)(woaT + j * 256 + k0) =
                make_uint4(pk2(f[0], f[1]), pk2(f[2], f[3]),
                           pk2(f[4], f[5]), pk2(f[6], f[7]));
        }
    } else {
        bias_oa[t] = b_off[t];
        if (t < 128) bias_oa[256 + t] = b_attn[t];
    }
}

// ======================= bf16 MFMA GEMM core (N-blocked, double-buffered) =====
template <int OUT_MODE, bool A_F32, int NB>
__device__ __forceinline__ void gemm_core(
    const void* __restrict__ Ap, const ushort_t* __restrict__ BT,
    const float* __restrict__ bias, void* __restrict__ Cp, int N,
    int bm, int bn, ushort_t* As, ushort_t* Bs)
{
    const int tid  = threadIdx.x;
    const int wave = tid >> 6, lane = tid & 63;
    const int wm = (wave >> 1) * 64, wn = (wave & 1) * 64;
    const int c0 = 2 * wave, c1 = 2 * wave + 1;
    const int kb = (lane & 3) * 8;
    const int ar0 = bm + c0 * 16 + (lane >> 2);
    const int ar1 = bm + c1 * 16 + (lane >> 2);
    const ushort_t* gA0h = nullptr; const ushort_t* gA1h = nullptr;
    const float*    gA0f = nullptr; const float*    gA1f = nullptr;
    if (A_F32) {
        gA0f = (const float*)Ap + (size_t)ar0 * 256 + kb;
        gA1f = (const float*)Ap + (size_t)ar1 * 256 + kb;
    } else {
        gA0h = (const ushort_t*)Ap + (size_t)ar0 * 256 + kb;
        gA1h = (const ushort_t*)Ap + (size_t)ar1 * 256 + kb;
    }
    const ushort_t* gB0[NB]; const ushort_t* gB1[NB];
#pragma unroll
    for (int nb = 0; nb < NB; nb++) {
        gB0[nb] = BT + (size_t)(bn + nb * 128 + c0 * 16 + (lane >> 2)) * 256 + kb;
        gB1[nb] = BT + (size_t)(bn + nb * 128 + c1 * 16 + (lane >> 2)) * 256 + kb;
    }

    auto STAGE = [&](int kt, int buf) {
        ushort_t* as = As + buf * 4096;
        ushort_t* bs = Bs + buf * (NB * 4096);
        if (A_F32) {
            const float* a0 = gA0f + kt * 32;
            const float* a1 = gA1f + kt * 32;
            float4 x0 = *(const float4*)a0;
            float4 x1 = *(const float4*)(a0 + 4);
            float4 y0 = *(const float4*)a1;
            float4 y1 = *(const float4*)(a1 + 4);
            *(uint4*)(as + c0 * 512 + lane * 8) =
                make_uint4(pk2(x0.x, x0.y), pk2(x0.z, x0.w),
                           pk2(x1.x, x1.y), pk2(x1.z, x1.w));
            *(uint4*)(as + c1 * 512 + lane * 8) =
                make_uint4(pk2(y0.x, y0.y), pk2(y0.z, y0.w),
                           pk2(y1.x, y1.y), pk2(y1.z, y1.w));
        } else {
            gld16(gA0h + kt * 32, as + c0 * 512);
            gld16(gA1h + kt * 32, as + c1 * 512);
        }
#pragma unroll
        for (int nb = 0; nb < NB; nb++) {
            gld16(gB0[nb] + kt * 32, bs + nb * 4096 + c0 * 512);
            gld16(gB1[nb] + kt * 32, bs + nb * 4096 + c1 * 512);
        }
    };

    f32x4 acc[NB][4][4] = {};
    const int row = lane & 15, kg = (lane >> 4) * 8;

    STAGE(0, 0);
    __syncthreads();

    for (int kt = 0; kt < 8; kt++) {
        const int cur = kt & 1;
        if (kt < 7) STAGE(kt + 1, cur ^ 1);
        const ushort_t* as = As + cur * 4096;
        const ushort_t* bs = Bs + cur * (NB * 4096);
        bf16x8 af[4];
#pragma unroll
        for (int i = 0; i < 4; i++)
            af[i] = *(const bf16x8*)(as + (wm + i * 16 + row) * 32 + kg);
#pragma unroll
        for (int nb = 0; nb < NB; nb++) {
            bf16x8 bfr[4];
#pragma unroll
            for (int j = 0; j < 4; j++)
                bfr[j] = *(const bf16x8*)(bs + nb * 4096 + (wn + j * 16 + row) * 32 + kg);
#pragma unroll
            for (int i = 0; i < 4; i++)
#pragma unroll
                for (int j = 0; j < 4; j++)
                    acc[nb][i][j] = __builtin_amdgcn_mfma_f32_16x16x32_bf16(
                        af[i], bfr[j], acc[nb][i][j], 0, 0, 0);
        }
        __syncthreads();
    }

    const int col = lane & 15, rbase = (lane >> 4) * 4;
#pragma unroll
    for (int nb = 0; nb < NB; nb++) {
#pragma unroll
        for (int j = 0; j < 4; j++) {
            const int cc = bn + nb * 128 + wn + j * 16 + col;
            const float bv = bias[cc];
#pragma unroll
            for (int i = 0; i < 4; i++) {
                const int rr = bm + wm + i * 16 + rbase;
#pragma unroll
                for (int r = 0; r < 4; r++) {
                    const float v = acc[nb][i][j][r] + bv;
                    const int m = rr + r;
                    if (OUT_MODE == 0) {
                        ((float*)Cp)[(size_t)m * N + cc] = v;
                    } else {
                        // value head-major: [b][head][pix][32]
                        const int bb  = m / LEN_IN;
                        const int pix = m - bb * LEN_IN;
                        const int head = cc >> 5, ch = cc & 31;
                        ((ushort_t*)Cp)[((size_t)((bb * 8 + head) * LEN_IN + pix) << 5) + ch] = bfbits(v);
                    }
                }
            }
        }
    }
}

// 510 blocks: [0,170) value NB=2; [170,340) offattn bn{0,128}; [340,510) offattn bn{256}
__global__ __launch_bounds__(256) void gemm_dual(
    const float* __restrict__ inflat, const ushort_t* __restrict__ wvT,
    const float* __restrict__ b_val, ushort_t* __restrict__ value_bf,
    const float* __restrict__ query, const ushort_t* __restrict__ woaT,
    const float* __restrict__ bias_oa, float* __restrict__ offattn)
{
    __shared__ ushort_t As[2 * 128 * 32];
    __shared__ ushort_t Bs[2 * 2 * 128 * 32];
    const int blk = blockIdx.x;
    if (blk < 170) {
        gemm_core<2, true, 2>(inflat, wvT, b_val, value_bf, 256,
                              blk * 128, 0, As, Bs);
    } else if (blk < 340) {
        gemm_core<0, true, 2>(query, woaT, bias_oa, offattn, 384,
                              (blk - 170) * 128, 0, As, Bs);
    } else {
        gemm_core<0, true, 1>(query, woaT, bias_oa, offattn, 384,
                              (blk - 340) * 128, 256, As, Bs);
    }
}

__global__ __launch_bounds__(256) void gemm_out(
    const ushort_t* __restrict__ mid_bf, const ushort_t* __restrict__ woutT,
    const float* __restrict__ b_out, float* __restrict__ out)
{
    __shared__ ushort_t As[2 * 128 * 32];
    __shared__ ushort_t Bs[2 * 128 * 32];
    const int bn = (blockIdx.x & 1) * 128, bm = (blockIdx.x >> 1) * 128;
    gemm_core<0, false, 1>(mid_bf, woutT, b_out, out, 256, bm, bn, As, Bs);
}

// ======================= softmax + bilinear sampling v6 =======================
// v4 phase-split (24.5 KB LDS, 6 blocks/CU) + phase-2 software pipeline:
// point pp+1's 4 corner loads are issued BEFORE point pp's accumulate, so
// each wave keeps 8 gather loads in flight instead of 4 (VGPR 40 -> ~70,
// still within the 85-VGPR budget for 6 waves/SIMD).
__device__ __forceinline__ void accd(f32x2& a, unsigned u, f32x2 w) {
    f32x2 v;
    v.x = __uint_as_float(u << 16);
    v.y = __uint_as_float(u & 0xFFFF0000u);
    a = w * v + a;   // ffp-contract -> v_pk_fma_f32
}
__device__ __forceinline__ void accp(f32x2* a, uint4 u, float wf) {
    const f32x2 w = {wf, wf};
    accd(a[0], u.x, w); accd(a[1], u.y, w);
    accd(a[2], u.z, w); accd(a[3], u.w, w);
}

__global__ __launch_bounds__(256) void msda_sample_v6(
    const ushort_t* __restrict__ value,   // [B*8][5440][32] bf16
    const float* __restrict__ refp,
    const float* __restrict__ offattn,
    ushort_t* __restrict__ mid)
{
    __shared__ float4 wLDS[64][16];       // 16 KB  (w00,w01,w10,w11)
    __shared__ int2   aLDS[64][16];       // 8 KB   (off00, dx<<16|dy)
    __shared__ float  esLDS[64];

    const int tid = threadIdx.x;
    const unsigned bid = blockIdx.x;
    // XCD-pinned slice mapping: 85 q-chunks per (b,h), 4 (b,h) per XCD
    const int xcd   = bid & 7;
    const int pos   = bid >> 3;           // 0..339
    const int slice = pos / 85;           // 0..3
    const int qc    = pos - slice * 85;   // 0..84
    const int bh    = xcd * 4 + slice;    // 0..31
    const int b     = bh >> 3, h = bh & 7;
    const int bqbase = b * LEN_Q + qc * 64;

    // ---------------- phase 1: per-(q,p) params, computed once ----------------
    {
        const int p  = tid & 15;
        const int qg = tid >> 4;          // 0..15
        const int l  = p >> 2;
        const int shift = 6 - l;
        const int W  = 1 << shift;
        const float fW   = (float)W;
        const float invW = __uint_as_float((unsigned)(127 - shift) << 23); // exact 2^-shift
        const int st = (l == 0) ? 0 : (l == 1) ? 4096 : (l == 2) ? 5120 : 5376;

#pragma unroll
        for (int it = 0; it < 4; it++) {
            const int ql = it * 16 + qg;  // 0..63
            const int bq = bqbase + ql;
            const float* oab = offattn + (size_t)bq * 384;
            const float2 off = *(const float2*)(oab + h * 32 + p * 2);
            const float  lgv = oab[256 + h * 16 + p];
            const float2 rl  = *(const float2*)(refp + (size_t)bq * 8 + l * 2);

            float mx = lgv;
            mx = fmaxf(mx, __shfl_xor(mx, 1));
            mx = fmaxf(mx, __shfl_xor(mx, 2));
            mx = fmaxf(mx, __shfl_xor(mx, 4));
            mx = fmaxf(mx, __shfl_xor(mx, 8));
            const float e = __expf(lgv - mx);
            float es = e;
            es += __shfl_xor(es, 1);
            es += __shfl_xor(es, 2);
            es += __shfl_xor(es, 4);
            es += __shfl_xor(es, 8);

            const float x = (rl.x + off.x * invW) * fW - 0.5f;
            const float y = (rl.y + off.y * invW) * fW - 0.5f;
            const float x0f = floorf(x), y0f = floorf(y);
            const float wx = x - x0f, wy = y - y0f;
            const int ix0 = (int)x0f, iy0 = (int)y0f;
            const int ix1 = ix0 + 1,  iy1 = iy0 + 1;
            const float vx0 = (ix0 >= 0 && ix0 < W) ? 1.f : 0.f;
            const float vx1 = (ix1 >= 0 && ix1 < W) ? 1.f : 0.f;
            const float vy0 = (iy0 >= 0 && iy0 < W) ? 1.f : 0.f;
            const float vy1 = (iy1 >= 0 && iy1 < W) ? 1.f : 0.f;
            const int cx0 = min(max(ix0, 0), W - 1);
            const int cx1 = min(max(ix1, 0), W - 1);
            const int cy0 = min(max(iy0, 0), W - 1);
            const int cy1 = min(max(iy1, 0), W - 1);
            const float hx0 = (1.f - wx) * vx0, hx1 = wx * vx1;
            const float hy0 = (1.f - wy) * vy0, hy1 = wy * vy1;

            const int off00 = (st + (cy0 << shift) + cx0) << 6;
            const int dxB   = (cx1 - cx0) << 6;                 // 0 or 64
            const int dyB   = ((cy1 - cy0) << shift) << 6;      // 0 .. 4096

            const int ps = p ^ (ql & 15); // XOR swizzle -> 2-way banks both phases
            wLDS[ql][ps] = make_float4(e * hx0 * hy0, e * hx1 * hy0,
                                       e * hx0 * hy1, e * hx1 * hy1);
            aLDS[ql][ps] = make_int2(off00, (dxB << 16) | dyB);
            if (p == 0) esLDS[ql] = es;
        }
    }
    __syncthreads();

    // ---------------- phase 2: gather + blend (2-point pipeline) ----------------
    const int ql = tid >> 2;              // 0..63
    const int cg = tid & 3;               // channel group (8 ch = 16 B)
    const int bq = bqbase + ql;
    const char* vb = (const char*)value + (size_t)bh * (LEN_IN * 64) + cg * 16;
    const float inv = 1.f / esLDS[ql];
    const int qs = ql & 15;

    f32x2 acc2[4];
#pragma unroll
    for (int d = 0; d < 4; d++) acc2[d] = (f32x2){0.f, 0.f};

    // prologue: issue point 0's loads
    float4 w;
    uint4 v00, v01, v10, v11;
    {
        const int2   ai = aLDS[ql][0 ^ qs];
        w = wLDS[ql][0 ^ qs];
        const int dx = ai.y >> 16;
        const int dy = ai.y & 0xFFFF;
        const char* c00 = vb + ai.x;
        v00 = *(const uint4*)(c00);
        v01 = *(const uint4*)(c00 + dx);
        v10 = *(const uint4*)(c00 + dy);
        v11 = *(const uint4*)(c00 + dx + dy);
    }
#pragma unroll
    for (int pp = 0; pp < 16; pp++) {
        uint4 n00, n01, n10, n11; float4 nw;
        if (pp < 15) {
            const int2 nai = aLDS[ql][(pp + 1) ^ qs];
            nw = wLDS[ql][(pp + 1) ^ qs];
            const int ndx = nai.y >> 16;
            const int ndy = nai.y & 0xFFFF;
            const char* nc = vb + nai.x;
            n00 = *(const uint4*)(nc);
            n01 = *(const uint4*)(nc + ndx);
            n10 = *(const uint4*)(nc + ndy);
            n11 = *(const uint4*)(nc + ndx + ndy);
        }
        accp(acc2, v00, w.x);
        accp(acc2, v01, w.y);
        accp(acc2, v10, w.z);
        accp(acc2, v11, w.w);
        if (pp < 15) { v00 = n00; v01 = n01; v10 = n10; v11 = n11; w = nw; }
    }

    uint4 o;
    o.x = pk2(acc2[0].x * inv, acc2[0].y * inv);
    o.y = pk2(acc2[1].x * inv, acc2[1].y * inv);
    o.z = pk2(acc2[2].x * inv, acc2[2].y * inv);
    o.w = pk2(acc2[3].x * inv, acc2[3].y * inv);
    ((uint4*)(mid + (size_t)bq * 256 + h * 32))[cg] = o;
}

// ======================= launch =======================
extern "C" void kernel_launch(void* const* d_in, const int* in_sizes, int n_in,
                              void* d_out, int out_size, void* d_ws, size_t ws_size,
                              hipStream_t stream)
{
    const float* query  = (const float*)d_in[0];
    const float* refp   = (const float*)d_in[1];
    const float* inflat = (const float*)d_in[2];
    const float* W_val  = (const float*)d_in[5];
    const float* b_val  = (const float*)d_in[6];
    const float* W_off  = (const float*)d_in[7];
    const float* W_attn = (const float*)d_in[9];
    const float* b_off  = (const float*)d_in[8];
    const float* b_attn = (const float*)d_in[10];
    const float* W_out  = (const float*)d_in[11];
    const float* b_out  = (const float*)d_in[12];
    float* out = (float*)d_out;

    char* ws = (char*)d_ws;
    ushort_t* mid_bf   = (ushort_t*)ws;                               // 11,141,120
    ushort_t* value_bf = (ushort_t*)(ws + 11141120);                  // 11,141,120 head-major
    ushort_t* wvT      = (ushort_t*)(ws + 22282240);                  // 131,072
    ushort_t* woutT    = (ushort_t*)(ws + 22413312);                  // 131,072
    ushort_t* woaT     = (ushort_t*)(ws + 22544384);                  // 196,608
    float*    bias_oa  = (float*)   (ws + 22740992);                  // 1,536
    float*    offattn  = (float*)   (ws + 22742528);                  // 33,423,360

    dim3 blk(256);
    pack_weights<<<dim3(97), blk, 0, stream>>>(
        W_val, W_out, W_off, W_attn, b_off, b_attn,
        wvT, woutT, woaT, bias_oa);
    gemm_dual<<<dim3(510), blk, 0, stream>>>(
        inflat, wvT, b_val, value_bf, query, woaT, bias_oa, offattn);
    msda_sample_v6<<<dim3(2720), blk, 0, stream>>>(
        value_bf, refp, offattn, mid_bf);
    gemm_out<<<dim3(340), blk, 0, stream>>>(
        mid_bf, woutT, b_out, out);
}

// Round 11
// 174.585 us; speedup vs baseline: 1.3180x; 1.3180x over previous
//
#include <hip/hip_runtime.h>
#include <hip/hip_bf16.h>
#include <math.h>

typedef unsigned short ushort_t;
typedef __attribute__((ext_vector_type(8))) short bf16x8;
typedef __attribute__((ext_vector_type(4))) float f32x4;
typedef __attribute__((ext_vector_type(2))) float f32x2;

constexpr int BATCH   = 4;
constexpr int D_MODEL = 256;
constexpr int LEN_IN  = 5440;
constexpr int LEN_Q   = 5440;
constexpr int M_TOT   = BATCH * LEN_Q;   // 21760

#define ASG __attribute__((address_space(1)))
#define ASL __attribute__((address_space(3)))

__device__ __forceinline__ void gld16(const void* g, void* l) {
    __builtin_amdgcn_global_load_lds((ASG const void*)g, (ASL void*)l, 16, 0, 0);
}

__device__ __forceinline__ ushort_t bfbits(float x) {
    __hip_bfloat16 h = __float2bfloat16(x);
    ushort_t u; __builtin_memcpy(&u, &h, 2); return u;
}
__device__ __forceinline__ unsigned pk2(float a, float b) {
    return (unsigned)bfbits(a) | ((unsigned)bfbits(b) << 16);
}

// ======================= weight prep (tiny) =======================
__global__ __launch_bounds__(256) void pack_weights(
    const float* __restrict__ Wv, const float* __restrict__ Wout,
    const float* __restrict__ Wo, const float* __restrict__ Wa,
    const float* __restrict__ b_off, const float* __restrict__ b_attn,
    ushort_t* __restrict__ wvT, ushort_t* __restrict__ woutT,
    ushort_t* __restrict__ woaT, float* __restrict__ bias_oa)
{
    const int blk = blockIdx.x, t = threadIdx.x;
    if (blk < 64) {
        const float* src = (blk < 32) ? Wv : Wout;
        ushort_t*    dst = (blk < 32) ? wvT : woutT;
        const int k0 = (blk & 31) * 8;
        float f[8];
#pragma unroll
        for (int i = 0; i < 8; i++) f[i] = src[(k0 + i) * 256 + t];
        *(uint4*)(dst + t * 256 + k0) =
            make_uint4(pk2(f[0], f[1]), pk2(f[2], f[3]),
                       pk2(f[4], f[5]), pk2(f[6], f[7]));
    } else if (blk < 96) {
        const int k0 = (blk - 64) * 8;
#pragma unroll
        for (int rep = 0; rep < 2; rep++) {
            const int j = (rep == 0) ? t : 256 + t;
            if (rep == 1 && t >= 128) break;
            float f[8];
#pragma unroll
            for (int i = 0; i < 8; i++)
                f[i] = (j < 256) ? Wo[(k0 + i) * 256 + j]
                                 : Wa[(k0 + i) * 128 + (j - 256)];
            *(uint4*)(woaT + j * 256 + k0) =
                make_uint4(pk2(f[0], f[1]), pk2(f[2], f[3]),
                           pk2(f[4], f[5]), pk2(f[6], f[7]));
        }
    } else {
        bias_oa[t] = b_off[t];
        if (t < 128) bias_oa[256 + t] = b_attn[t];
    }
}

// ======================= bf16 MFMA GEMM core (N-blocked, double-buffered) =====
template <int OUT_MODE, bool A_F32, int NB>
__device__ __forceinline__ void gemm_core(
    const void* __restrict__ Ap, const ushort_t* __restrict__ BT,
    const float* __restrict__ bias, void* __restrict__ Cp, int N,
    int bm, int bn, ushort_t* As, ushort_t* Bs)
{
    const int tid  = threadIdx.x;
    const int wave = tid >> 6, lane = tid & 63;
    const int wm = (wave >> 1) * 64, wn = (wave & 1) * 64;
    const int c0 = 2 * wave, c1 = 2 * wave + 1;
    const int kb = (lane & 3) * 8;
    const int ar0 = bm + c0 * 16 + (lane >> 2);
    const int ar1 = bm + c1 * 16 + (lane >> 2);
    const ushort_t* gA0h = nullptr; const ushort_t* gA1h = nullptr;
    const float*    gA0f = nullptr; const float*    gA1f = nullptr;
    if (A_F32) {
        gA0f = (const float*)Ap + (size_t)ar0 * 256 + kb;
        gA1f = (const float*)Ap + (size_t)ar1 * 256 + kb;
    } else {
        gA0h = (const ushort_t*)Ap + (size_t)ar0 * 256 + kb;
        gA1h = (const ushort_t*)Ap + (size_t)ar1 * 256 + kb;
    }
    const ushort_t* gB0[NB]; const ushort_t* gB1[NB];
#pragma unroll
    for (int nb = 0; nb < NB; nb++) {
        gB0[nb] = BT + (size_t)(bn + nb * 128 + c0 * 16 + (lane >> 2)) * 256 + kb;
        gB1[nb] = BT + (size_t)(bn + nb * 128 + c1 * 16 + (lane >> 2)) * 256 + kb;
    }

    auto STAGE = [&](int kt, int buf) {
        ushort_t* as = As + buf * 4096;
        ushort_t* bs = Bs + buf * (NB * 4096);
        if (A_F32) {
            const float* a0 = gA0f + kt * 32;
            const float* a1 = gA1f + kt * 32;
            float4 x0 = *(const float4*)a0;
            float4 x1 = *(const float4*)(a0 + 4);
            float4 y0 = *(const float4*)a1;
            float4 y1 = *(const float4*)(a1 + 4);
            *(uint4*)(as + c0 * 512 + lane * 8) =
                make_uint4(pk2(x0.x, x0.y), pk2(x0.z, x0.w),
                           pk2(x1.x, x1.y), pk2(x1.z, x1.w));
            *(uint4*)(as + c1 * 512 + lane * 8) =
                make_uint4(pk2(y0.x, y0.y), pk2(y0.z, y0.w),
                           pk2(y1.x, y1.y), pk2(y1.z, y1.w));
        } else {
            gld16(gA0h + kt * 32, as + c0 * 512);
            gld16(gA1h + kt * 32, as + c1 * 512);
        }
#pragma unroll
        for (int nb = 0; nb < NB; nb++) {
            gld16(gB0[nb] + kt * 32, bs + nb * 4096 + c0 * 512);
            gld16(gB1[nb] + kt * 32, bs + nb * 4096 + c1 * 512);
        }
    };

    f32x4 acc[NB][4][4] = {};
    const int row = lane & 15, kg = (lane >> 4) * 8;

    STAGE(0, 0);
    __syncthreads();

    for (int kt = 0; kt < 8; kt++) {
        const int cur = kt & 1;
        if (kt < 7) STAGE(kt + 1, cur ^ 1);
        const ushort_t* as = As + cur * 4096;
        const ushort_t* bs = Bs + cur * (NB * 4096);
        bf16x8 af[4];
#pragma unroll
        for (int i = 0; i < 4; i++)
            af[i] = *(const bf16x8*)(as + (wm + i * 16 + row) * 32 + kg);
#pragma unroll
        for (int nb = 0; nb < NB; nb++) {
            bf16x8 bfr[4];
#pragma unroll
            for (int j = 0; j < 4; j++)
                bfr[j] = *(const bf16x8*)(bs + nb * 4096 + (wn + j * 16 + row) * 32 + kg);
#pragma unroll
            for (int i = 0; i < 4; i++)
#pragma unroll
                for (int j = 0; j < 4; j++)
                    acc[nb][i][j] = __builtin_amdgcn_mfma_f32_16x16x32_bf16(
                        af[i], bfr[j], acc[nb][i][j], 0, 0, 0);
        }
        __syncthreads();
    }

    const int col = lane & 15, rbase = (lane >> 4) * 4;
#pragma unroll
    for (int nb = 0; nb < NB; nb++) {
#pragma unroll
        for (int j = 0; j < 4; j++) {
            const int cc = bn + nb * 128 + wn + j * 16 + col;
            const float bv = bias[cc];
#pragma unroll
            for (int i = 0; i < 4; i++) {
                const int rr = bm + wm + i * 16 + rbase;
#pragma unroll
                for (int r = 0; r < 4; r++) {
                    const float v = acc[nb][i][j][r] + bv;
                    const int m = rr + r;
                    if (OUT_MODE == 0) {
                        ((float*)Cp)[(size_t)m * N + cc] = v;
                    } else {
                        // value head-major: [b][head][pix][32]
                        const int bb  = m / LEN_IN;
                        const int pix = m - bb * LEN_IN;
                        const int head = cc >> 5, ch = cc & 31;
                        ((ushort_t*)Cp)[((size_t)((bb * 8 + head) * LEN_IN + pix) << 5) + ch] = bfbits(v);
                    }
                }
            }
        }
    }
}

// 510 blocks: [0,170) value NB=2; [170,340) offattn bn{0,128}; [340,510) offattn bn{256}
__global__ __launch_bounds__(256) void gemm_dual(
    const float* __restrict__ inflat, const ushort_t* __restrict__ wvT,
    const float* __restrict__ b_val, ushort_t* __restrict__ value_bf,
    const float* __restrict__ query, const ushort_t* __restrict__ woaT,
    const float* __restrict__ bias_oa, float* __restrict__ offattn)
{
    __shared__ ushort_t As[2 * 128 * 32];
    __shared__ ushort_t Bs[2 * 2 * 128 * 32];
    const int blk = blockIdx.x;
    if (blk < 170) {
        gemm_core<2, true, 2>(inflat, wvT, b_val, value_bf, 256,
                              blk * 128, 0, As, Bs);
    } else if (blk < 340) {
        gemm_core<0, true, 2>(query, woaT, bias_oa, offattn, 384,
                              (blk - 170) * 128, 0, As, Bs);
    } else {
        gemm_core<0, true, 1>(query, woaT, bias_oa, offattn, 384,
                              (blk - 340) * 128, 256, As, Bs);
    }
}

__global__ __launch_bounds__(256) void gemm_out(
    const ushort_t* __restrict__ mid_bf, const ushort_t* __restrict__ woutT,
    const float* __restrict__ b_out, float* __restrict__ out)
{
    __shared__ ushort_t As[2 * 128 * 32];
    __shared__ ushort_t Bs[2 * 128 * 32];
    const int bn = (blockIdx.x & 1) * 128, bm = (blockIdx.x >> 1) * 128;
    gemm_core<0, false, 1>(mid_bf, woutT, b_out, out, 256, bm, bn, As, Bs);
}

// ======================= softmax + bilinear sampling v7 =======================
// v4 phase-split + PAIRWISE phase-2: each loop body loads BOTH points' 8
// corner-uint4s before accumulating either -> 8 loads in flight (vs v4's 4)
// with bounded liveness. __launch_bounds__(256,6) hard-caps VGPR at 85
// (preventing the v6-style full-pipeline blowup to 256) and matches the
// 6 blocks/CU that 24.5 KB LDS permits.
__device__ __forceinline__ void accd(f32x2& a, unsigned u, f32x2 w) {
    f32x2 v;
    v.x = __uint_as_float(u << 16);
    v.y = __uint_as_float(u & 0xFFFF0000u);
    a = w * v + a;   // ffp-contract -> v_pk_fma_f32
}
__device__ __forceinline__ void accp(f32x2* a, uint4 u, float wf) {
    const f32x2 w = {wf, wf};
    accd(a[0], u.x, w); accd(a[1], u.y, w);
    accd(a[2], u.z, w); accd(a[3], u.w, w);
}

__global__ __launch_bounds__(256, 6) void msda_sample_v7(
    const ushort_t* __restrict__ value,   // [B*8][5440][32] bf16
    const float* __restrict__ refp,
    const float* __restrict__ offattn,
    ushort_t* __restrict__ mid)
{
    __shared__ float4 wLDS[64][16];       // 16 KB  (w00,w01,w10,w11)
    __shared__ int2   aLDS[64][16];       // 8 KB   (off00, dx<<16|dy)
    __shared__ float  esLDS[64];

    const int tid = threadIdx.x;
    const unsigned bid = blockIdx.x;
    // XCD-pinned slice mapping: 85 q-chunks per (b,h), 4 (b,h) per XCD
    const int xcd   = bid & 7;
    const int pos   = bid >> 3;           // 0..339
    const int slice = pos / 85;           // 0..3
    const int qc    = pos - slice * 85;   // 0..84
    const int bh    = xcd * 4 + slice;    // 0..31
    const int b     = bh >> 3, h = bh & 7;
    const int bqbase = b * LEN_Q + qc * 64;

    // ---------------- phase 1: per-(q,p) params, computed once ----------------
    {
        const int p  = tid & 15;
        const int qg = tid >> 4;          // 0..15
        const int l  = p >> 2;
        const int shift = 6 - l;
        const int W  = 1 << shift;
        const float fW   = (float)W;
        const float invW = __uint_as_float((unsigned)(127 - shift) << 23); // exact 2^-shift
        const int st = (l == 0) ? 0 : (l == 1) ? 4096 : (l == 2) ? 5120 : 5376;

#pragma unroll
        for (int it = 0; it < 4; it++) {
            const int ql = it * 16 + qg;  // 0..63
            const int bq = bqbase + ql;
            const float* oab = offattn + (size_t)bq * 384;
            const float2 off = *(const float2*)(oab + h * 32 + p * 2);
            const float  lgv = oab[256 + h * 16 + p];
            const float2 rl  = *(const float2*)(refp + (size_t)bq * 8 + l * 2);

            float mx = lgv;
            mx = fmaxf(mx, __shfl_xor(mx, 1));
            mx = fmaxf(mx, __shfl_xor(mx, 2));
            mx = fmaxf(mx, __shfl_xor(mx, 4));
            mx = fmaxf(mx, __shfl_xor(mx, 8));
            const float e = __expf(lgv - mx);
            float es = e;
            es += __shfl_xor(es, 1);
            es += __shfl_xor(es, 2);
            es += __shfl_xor(es, 4);
            es += __shfl_xor(es, 8);

            const float x = (rl.x + off.x * invW) * fW - 0.5f;
            const float y = (rl.y + off.y * invW) * fW - 0.5f;
            const float x0f = floorf(x), y0f = floorf(y);
            const float wx = x - x0f, wy = y - y0f;
            const int ix0 = (int)x0f, iy0 = (int)y0f;
            const int ix1 = ix0 + 1,  iy1 = iy0 + 1;
            const float vx0 = (ix0 >= 0 && ix0 < W) ? 1.f : 0.f;
            const float vx1 = (ix1 >= 0 && ix1 < W) ? 1.f : 0.f;
            const float vy0 = (iy0 >= 0 && iy0 < W) ? 1.f : 0.f;
            const float vy1 = (iy1 >= 0 && iy1 < W) ? 1.f : 0.f;
            const int cx0 = min(max(ix0, 0), W - 1);
            const int cx1 = min(max(ix1, 0), W - 1);
            const int cy0 = min(max(iy0, 0), W - 1);
            const int cy1 = min(max(iy1, 0), W - 1);
            const float hx0 = (1.f - wx) * vx0, hx1 = wx * vx1;
            const float hy0 = (1.f - wy) * vy0, hy1 = wy * vy1;

            const int off00 = (st + (cy0 << shift) + cx0) << 6;
            const int dxB   = (cx1 - cx0) << 6;                 // 0 or 64
            const int dyB   = ((cy1 - cy0) << shift) << 6;      // 0 .. 4096

            const int ps = p ^ (ql & 15); // XOR swizzle -> 2-way banks both phases
            wLDS[ql][ps] = make_float4(e * hx0 * hy0, e * hx1 * hy0,
                                       e * hx0 * hy1, e * hx1 * hy1);
            aLDS[ql][ps] = make_int2(off00, (dxB << 16) | dyB);
            if (p == 0) esLDS[ql] = es;
        }
    }
    __syncthreads();

    // ---------------- phase 2: gather + blend (pairwise points) ----------------
    const int ql = tid >> 2;              // 0..63
    const int cg = tid & 3;               // channel group (8 ch = 16 B)
    const int bq = bqbase + ql;
    const char* vb = (const char*)value + (size_t)bh * (LEN_IN * 64) + cg * 16;
    const float inv = 1.f / esLDS[ql];
    const int qs = ql & 15;

    f32x2 acc2[4];
#pragma unroll
    for (int d = 0; d < 4; d++) acc2[d] = (f32x2){0.f, 0.f};

#pragma unroll
    for (int j = 0; j < 8; j++) {
        const int2   a0 = aLDS[ql][(2 * j) ^ qs];
        const int2   a1 = aLDS[ql][(2 * j + 1) ^ qs];
        const float4 w0 = wLDS[ql][(2 * j) ^ qs];
        const float4 w1 = wLDS[ql][(2 * j + 1) ^ qs];
        const int dx0 = a0.y >> 16, dy0 = a0.y & 0xFFFF;
        const int dx1 = a1.y >> 16, dy1 = a1.y & 0xFFFF;
        const char* c0 = vb + a0.x;
        const char* c1 = vb + a1.x;
        uint4 p00 = *(const uint4*)(c0);
        uint4 p01 = *(const uint4*)(c0 + dx0);
        uint4 p10 = *(const uint4*)(c0 + dy0);
        uint4 p11 = *(const uint4*)(c0 + dx0 + dy0);
        uint4 q00 = *(const uint4*)(c1);
        uint4 q01 = *(const uint4*)(c1 + dx1);
        uint4 q10 = *(const uint4*)(c1 + dy1);
        uint4 q11 = *(const uint4*)(c1 + dx1 + dy1);
        accp(acc2, p00, w0.x);
        accp(acc2, p01, w0.y);
        accp(acc2, p10, w0.z);
        accp(acc2, p11, w0.w);
        accp(acc2, q00, w1.x);
        accp(acc2, q01, w1.y);
        accp(acc2, q10, w1.z);
        accp(acc2, q11, w1.w);
    }

    uint4 o;
    o.x = pk2(acc2[0].x * inv, acc2[0].y * inv);
    o.y = pk2(acc2[1].x * inv, acc2[1].y * inv);
    o.z = pk2(acc2[2].x * inv, acc2[2].y * inv);
    o.w = pk2(acc2[3].x * inv, acc2[3].y * inv);
    ((uint4*)(mid + (size_t)bq * 256 + h * 32))[cg] = o;
}

// ======================= launch =======================
extern "C" void kernel_launch(void* const* d_in, const int* in_sizes, int n_in,
                              void* d_out, int out_size, void* d_ws, size_t ws_size,
                              hipStream_t stream)
{
    const float* query  = (const float*)d_in[0];
    const float* refp   = (const float*)d_in[1];
    const float* inflat = (const float*)d_in[2];
    const float* W_val  = (const float*)d_in[5];
    const float* b_val  = (const float*)d_in[6];
    const float* W_off  = (const float*)d_in[7];
    const float* W_attn = (const float*)d_in[9];
    const float* b_off  = (const float*)d_in[8];
    const float* b_attn = (const float*)d_in[10];
    const float* W_out  = (const float*)d_in[11];
    const float* b_out  = (const float*)d_in[12];
    float* out = (float*)d_out;

    char* ws = (char*)d_ws;
    ushort_t* mid_bf   = (ushort_t*)ws;                               // 11,141,120
    ushort_t* value_bf = (ushort_t*)(ws + 11141120);                  // 11,141,120 head-major
    ushort_t* wvT      = (ushort_t*)(ws + 22282240);                  // 131,072
    ushort_t* woutT    = (ushort_t*)(ws + 22413312);                  // 131,072
    ushort_t* woaT     = (ushort_t*)(ws + 22544384);                  // 196,608
    float*    bias_oa  = (float*)   (ws + 22740992);                  // 1,536
    float*    offattn  = (float*)   (ws + 22742528);                  // 33,423,360

    dim3 blk(256);
    pack_weights<<<dim3(97), blk, 0, stream>>>(
        W_val, W_out, W_off, W_attn, b_off, b_attn,
        wvT, woutT, woaT, bias_oa);
    gemm_dual<<<dim3(510), blk, 0, stream>>>(
        inflat, wvT, b_val, value_bf, query, woaT, bias_oa, offattn);
    msda_sample_v7<<<dim3(2720), blk, 0, stream>>>(
        value_bf, refp, offattn, mid_bf);
    gemm_out<<<dim3(340), blk, 0, stream>>>(
        mid_bf, woutT, b_out, out);
}